// Round 1
// baseline (4418.306 us; speedup 1.0000x reference)
//
#include <hip/hip_runtime.h>
#include <hip/hip_fp16.h>
#include <cstdint>
#include <cstddef>
#include <cstring>

#define T_SEQ 512
#define NB 32

__device__ __forceinline__ uint32_t agent_load_u32(const uint32_t* p) {
    return __hip_atomic_load(p, __ATOMIC_RELAXED, __HIP_MEMORY_SCOPE_AGENT);
}
__device__ __forceinline__ void agent_store_u32(uint32_t* p, uint32_t v) {
    __hip_atomic_store(p, v, __ATOMIC_RELAXED, __HIP_MEMORY_SCOPE_AGENT);
}
__device__ __forceinline__ float hbits2f(unsigned short us) {
    __half h; __builtin_memcpy(&h, &us, 2); return __half2float(h);
}

// =====================================================================
// rec512_fused: layers 0 and 1 run CONCURRENTLY.
//   blocks   0..255 = layer-0 slices (b = bid&31, s = bid>>5)
//   blocks 256..511 = layer-1 slices (same decomposition, same XCD as
//                     its layer-0 producers under %8 round-robin).
// 2 blocks/CU (VGPR<=64 forced via launch_bounds(1024,8)): one layer's
// poll/barrier stalls hide under the co-resident other layer's issue.
// Cross-layer handoff: l0 epilogue packs 64 relu outputs into 32 u32
// words (same [2 rows/word] layout as the old r0h), agent-stores them to
// r0w[b][t][256], drains vmcnt(0), then bumps prog0[b][s]=t+1. l1's
// staging lanes poll prog0 >= t+2 then agent-load the words. Dependency
// is one-directional (l0 never waits on l1) => acyclic, no deadlock;
// losing co-residency only degrades to serial execution.
// Within-layer h exchange: unchanged parity-tagged hpk protocol.
// =====================================================================
__global__ __launch_bounds__(1024, 8) void rec512_fused(
    const float* __restrict__ x,
    const float* __restrict__ Wih0, const float* __restrict__ Whh0,
    const float* __restrict__ bih0, const float* __restrict__ bhh0,
    const float* __restrict__ Wih1, const float* __restrict__ Whh1,
    const float* __restrict__ bih1, const float* __restrict__ bhh1,
    uint32_t* __restrict__ r0w,        // [NB][T][256] relu0 fp16 pairs
    unsigned short* __restrict__ r1h,  // [NB][T][512] fp16 bits
    uint32_t* __restrict__ hpk0, uint32_t* __restrict__ hpk1,
    uint32_t* __restrict__ prog0)      // [NB][8] layer-0 step counters
{
    __shared__ float hbuf[2][512];
    __shared__ float abuf[2][512];     // l0: x staging (128 used); l1: relu0
    __shared__ float part[16][64];

    const int tid = threadIdx.x;
    const int bb  = blockIdx.x & 255;
    const int b   = bb & 31;
    const int s   = bb >> 5;           // 0..7
    const int jl  = tid & 63;
    const int kq  = tid >> 6;          // 0..15, wave-uniform
    const int row = (s << 6) + jl;
    const bool own = (kq == s);        // for tid<512 poll lanes
    const int myrow = (s << 6) + tid;  // epilogue lanes tid<64

    if (blockIdx.x < 256) {
        // ------------------------- layer 0 -------------------------
        __half2 wh[16], wi[4];
        {
            const float4* p4 = (const float4*)(Whh0 + (size_t)row * 512 + (kq << 5));
#pragma unroll
            for (int i = 0; i < 8; i++) {
                const float4 v = p4[i];
                wh[2 * i]     = __floats2half2_rn(v.x, v.y);
                wh[2 * i + 1] = __floats2half2_rn(v.z, v.w);
            }
            const float4* q4 = (const float4*)(Wih0 + (size_t)row * 128 + (kq << 3));
#pragma unroll
            for (int i = 0; i < 2; i++) {
                const float4 v = q4[i];
                wi[2 * i]     = __floats2half2_rn(v.x, v.y);
                wi[2 * i + 1] = __floats2half2_rn(v.z, v.w);
            }
        }
        float bias = 0.f;
        if (tid < 64) { const int r = (s << 6) + tid; bias = bih0[r] + bhh0[r]; }

        const float* x_b = x + (size_t)b * (T_SEQ * 128);
        uint32_t* r0_b = r0w + (size_t)b * (T_SEQ * 256);
        uint32_t* hp_b = hpk0 + (b << 10);

        if (tid < 128) abuf[0][tid] = x_b[tid];
        __syncthreads();

        for (int t = 0; t < T_SEQ; t++) {
            const int p = t & 1;
            float xn = 0.f;
            if (tid < 128 && t + 1 < T_SEQ) xn = x_b[(t + 1) * 128 + tid];

            if (t > 0 && tid < 512 && !own) {
                const uint32_t wtag = (uint32_t)t;
                uint32_t* sp = hp_b + (p << 9) + tid;
                uint32_t v;
                do { v = agent_load_u32(sp); } while ((v & 0xffffu) != wtag);
                hbuf[p][tid] = hbits2f((unsigned short)(v >> 16));
            }
            __syncthreads();   // B1
            if (tid < 128 && t + 1 < T_SEQ) abuf[(t + 1) & 1][tid] = xn;

            float a0 = 0.f, a1 = 0.f, a2 = 0.f, a3 = 0.f;
            if (t > 0) {
                const float4* hq = (const float4*)(&hbuf[p][kq << 5]);
#pragma unroll
                for (int i = 0; i < 8; i++) {
                    const float4 h4 = hq[i];
                    a0 = fmaf(__low2float(wh[2 * i]),      h4.x, a0);
                    a1 = fmaf(__high2float(wh[2 * i]),     h4.y, a1);
                    a2 = fmaf(__low2float(wh[2 * i + 1]),  h4.z, a2);
                    a3 = fmaf(__high2float(wh[2 * i + 1]), h4.w, a3);
                }
            }
            {
                const float4* xq = (const float4*)(&abuf[p][kq << 3]);
#pragma unroll
                for (int i = 0; i < 2; i++) {
                    const float4 x4 = xq[i];
                    a0 = fmaf(__low2float(wi[2 * i]),      x4.x, a0);
                    a1 = fmaf(__high2float(wi[2 * i]),     x4.y, a1);
                    a2 = fmaf(__low2float(wi[2 * i + 1]),  x4.z, a2);
                    a3 = fmaf(__high2float(wi[2 * i + 1]), x4.w, a3);
                }
            }
            part[kq][jl] = (a0 + a1) + (a2 + a3);
            __syncthreads();   // B2
            if (tid < 64) {
                const int p2 = (t + 1) & 1;
                float v = bias;
#pragma unroll
                for (int q = 0; q < 16; q++) v += part[q][tid];
                const float hv = tanhf(v);
                const __half hf = __float2half_rn(hv);
                unsigned short us; __builtin_memcpy(&us, &hf, 2);
                agent_store_u32(hp_b + (p2 << 9) + myrow,
                                ((uint32_t)us << 16) | (uint32_t)(t + 1));
                hbuf[p2][myrow] = hbits2f(us);
                // pack relu pairs: word w holds rows (2w, 2w+1) — same
                // layout the old u32 view of r0h had.
                const uint32_t ru = (us & 0x8000u) ? 0u : (uint32_t)us;
                const uint32_t vlo = (uint32_t)__shfl((int)ru, (tid << 1) & 63, 64);
                const uint32_t vhi = (uint32_t)__shfl((int)ru, ((tid << 1) + 1) & 63, 64);
                if (tid < 32)
                    agent_store_u32(r0_b + (size_t)t * 256 + (s << 5) + tid,
                                    (vhi << 16) | vlo);
                asm volatile("s_waitcnt vmcnt(0)" ::: "memory");
                if (tid == 0)
                    agent_store_u32(prog0 + (b << 3) + s, (uint32_t)(t + 1));
            }
            // next step's B1 orders everything else
        }
    } else {
        // ------------------------- layer 1 -------------------------
        __half2 wi[16], wh[16];
        {
            const float4* p4 = (const float4*)(Wih1 + (size_t)row * 512 + (kq << 5));
#pragma unroll
            for (int i = 0; i < 8; i++) {
                const float4 v = p4[i];
                wi[2 * i]     = __floats2half2_rn(v.x, v.y);
                wi[2 * i + 1] = __floats2half2_rn(v.z, v.w);
            }
            p4 = (const float4*)(Whh1 + (size_t)row * 512 + (kq << 5));
#pragma unroll
            for (int i = 0; i < 8; i++) {
                const float4 v = p4[i];
                wh[2 * i]     = __floats2half2_rn(v.x, v.y);
                wh[2 * i + 1] = __floats2half2_rn(v.z, v.w);
            }
        }
        float bias = 0.f;
        if (tid < 64) { const int r = (s << 6) + tid; bias = bih1[r] + bhh1[r]; }

        const uint32_t* r0_b = r0w + (size_t)b * (T_SEQ * 256);
        unsigned short* r1_b = r1h + (size_t)b * (T_SEQ * 512);
        uint32_t* hp_b = hpk1 + (b << 10);
        const int wlane = tid - 512;   // 0..255 staging lanes
        const bool stager = (tid >= 512 && tid < 768);
        const uint32_t* myprog = prog0 + (b << 3) + (stager ? (wlane >> 5) : 0);

        if (stager) {
            uint32_t pv;
            do { pv = agent_load_u32(myprog); } while (pv == 0u);   // l0 step 0 done
            asm volatile("" ::: "memory");
            const uint32_t v = agent_load_u32(r0_b + wlane);        // r0(0) pairs
            abuf[0][2 * wlane]     = hbits2f((unsigned short)(v & 0xffffu));
            abuf[0][2 * wlane + 1] = hbits2f((unsigned short)(v >> 16));
        }
        __syncthreads();

        for (int t = 0; t < T_SEQ; t++) {
            const int p = t & 1;
            uint32_t rn = 0;
            if (stager && t + 1 < T_SEQ) {
                const uint32_t need = (uint32_t)(t + 2);            // l0 step t+1 done
                uint32_t pv;
                do { pv = agent_load_u32(myprog); } while (pv < need);
                asm volatile("" ::: "memory");
                rn = agent_load_u32(r0_b + (size_t)(t + 1) * 256 + wlane);
            }
            if (t > 0 && tid < 512 && !own) {
                const uint32_t wtag = (uint32_t)t;
                uint32_t* sp = hp_b + (p << 9) + tid;
                uint32_t v;
                do { v = agent_load_u32(sp); } while ((v & 0xffffu) != wtag);
                hbuf[p][tid] = hbits2f((unsigned short)(v >> 16));
            }
            __syncthreads();   // B1
            if (stager && t + 1 < T_SEQ) {
                abuf[(t + 1) & 1][2 * wlane]     = hbits2f((unsigned short)(rn & 0xffffu));
                abuf[(t + 1) & 1][2 * wlane + 1] = hbits2f((unsigned short)(rn >> 16));
            }

            float a0 = 0.f, a1 = 0.f, a2 = 0.f, a3 = 0.f;
            {
                const float4* rq = (const float4*)(&abuf[p][kq << 5]);
#pragma unroll
                for (int i = 0; i < 8; i++) {
                    const float4 h4 = rq[i];
                    a0 = fmaf(__low2float(wi[2 * i]),      h4.x, a0);
                    a1 = fmaf(__high2float(wi[2 * i]),     h4.y, a1);
                    a2 = fmaf(__low2float(wi[2 * i + 1]),  h4.z, a2);
                    a3 = fmaf(__high2float(wi[2 * i + 1]), h4.w, a3);
                }
            }
            if (t > 0) {
                const float4* hq = (const float4*)(&hbuf[p][kq << 5]);
#pragma unroll
                for (int i = 0; i < 8; i++) {
                    const float4 h4 = hq[i];
                    a0 = fmaf(__low2float(wh[2 * i]),      h4.x, a0);
                    a1 = fmaf(__high2float(wh[2 * i]),     h4.y, a1);
                    a2 = fmaf(__low2float(wh[2 * i + 1]),  h4.z, a2);
                    a3 = fmaf(__high2float(wh[2 * i + 1]), h4.w, a3);
                }
            }
            part[kq][jl] = (a0 + a1) + (a2 + a3);
            __syncthreads();   // B2
            if (tid < 64) {
                const int p2 = (t + 1) & 1;
                float v = bias;
#pragma unroll
                for (int q = 0; q < 16; q++) v += part[q][tid];
                const float hv = tanhf(v);
                const __half hf = __float2half_rn(hv);
                unsigned short us; __builtin_memcpy(&us, &hf, 2);
                agent_store_u32(hp_b + (p2 << 9) + myrow,
                                ((uint32_t)us << 16) | (uint32_t)(t + 1));
                hbuf[p2][myrow] = hbits2f(us);
                r1_b[(size_t)t * 512 + myrow] = (us & 0x8000u) ? (unsigned short)0 : us;
            }
        }
    }
}

// =====================================================================
// gemm2h: xp2 = relu1(fp16) @ Wih2^T + (bi+bh), fp16 out. (proven r10)
// =====================================================================
#define BM 64
#define BK 32
#define AS_STRIDE 68
#define BS_STRIDE 132

__global__ __launch_bounds__(256, 4) void gemm2h(
    const unsigned short* __restrict__ A,   // [M,512] fp16 bits
    const float* __restrict__ W,            // [128,512]
    const float* __restrict__ bi, const float* __restrict__ bh,
    unsigned short* __restrict__ C,         // [M,128] fp16 bits
    int M, int K)
{
    __shared__ float As[BK][AS_STRIDE];
    __shared__ float Bs[BK][BS_STRIDE];
    const int tid = threadIdx.x;
    const int tx = tid & 15, ty = tid >> 4;
    const int m0 = blockIdx.x * BM;
    const int lr = tid >> 3, lc = (tid & 7) << 2;

    float acc[4][8];
#pragma unroll
    for (int i = 0; i < 4; i++)
#pragma unroll
        for (int j = 0; j < 8; j++) acc[i][j] = 0.f;

    for (int k0 = 0; k0 < K; k0 += BK) {
#pragma unroll
        for (int p = 0; p < 2; p++) {
            const int m = p * 32 + lr;
            const uint2 u = *(const uint2*)(A + (size_t)(m0 + m) * K + k0 + lc);
            As[lc + 0][m] = hbits2f((unsigned short)(u.x & 0xffffu));
            As[lc + 1][m] = hbits2f((unsigned short)(u.x >> 16));
            As[lc + 2][m] = hbits2f((unsigned short)(u.y & 0xffffu));
            As[lc + 3][m] = hbits2f((unsigned short)(u.y >> 16));
        }
#pragma unroll
        for (int p = 0; p < 4; p++) {
            const int n = p * 32 + lr;
            const float4 b4 = *(const float4*)(W + (size_t)n * K + k0 + lc);
            Bs[lc + 0][n] = b4.x; Bs[lc + 1][n] = b4.y;
            Bs[lc + 2][n] = b4.z; Bs[lc + 3][n] = b4.w;
        }
        __syncthreads();
#pragma unroll
        for (int kk = 0; kk < BK; kk++) {
            const float4 a4  = *(const float4*)&As[kk][tx << 2];
            const float4 b4a = *(const float4*)&Bs[kk][ty << 3];
            const float4 b4b = *(const float4*)&Bs[kk][(ty << 3) + 4];
            const float a[4] = { a4.x, a4.y, a4.z, a4.w };
            const float b[8] = { b4a.x, b4a.y, b4a.z, b4a.w, b4b.x, b4b.y, b4b.z, b4b.w };
#pragma unroll
            for (int i = 0; i < 4; i++)
#pragma unroll
                for (int j = 0; j < 8; j++) acc[i][j] = fmaf(a[i], b[j], acc[i][j]);
        }
        __syncthreads();
    }
    const int nbase = ty << 3;
    const float4 bia = *(const float4*)(bi + nbase);
    const float4 bib = *(const float4*)(bi + nbase + 4);
    const float4 bha = *(const float4*)(bh + nbase);
    const float4 bhb = *(const float4*)(bh + nbase + 4);
    const float bt[8] = { bia.x + bha.x, bia.y + bha.y, bia.z + bha.z, bia.w + bha.w,
                          bib.x + bhb.x, bib.y + bhb.y, bib.z + bhb.z, bib.w + bhb.w };
#pragma unroll
    for (int i = 0; i < 4; i++) {
        const int row = m0 + (tx << 2) + i;
        uint32_t pk[4];
#pragma unroll
        for (int j = 0; j < 4; j++) {
            const __half hlo = __float2half_rn(acc[i][2 * j]     + bt[2 * j]);
            const __half hhi = __float2half_rn(acc[i][2 * j + 1] + bt[2 * j + 1]);
            unsigned short lo, hi;
            __builtin_memcpy(&lo, &hlo, 2); __builtin_memcpy(&hi, &hhi, 2);
            pk[j] = ((uint32_t)hi << 16) | lo;
        }
        *(uint4*)(C + (size_t)row * 128 + nbase) = make_uint4(pk[0], pk[1], pk[2], pk[3]);
    }
}

// =====================================================================
// Layer 2 recurrence (H=128), xp fp16. One WG/batch; LDS-only. (proven)
// =====================================================================
__global__ __launch_bounds__(256, 4) void rec128h(
    const float* __restrict__ Whh,          // [128,128]
    const unsigned short* __restrict__ xp,  // [NB,T,128] fp16 bits
    float* __restrict__ out,                // [NB,T,128]
    float* __restrict__ hn)                 // [NB,128]
{
    const int tid = threadIdx.x;
    const int b  = blockIdx.x;
    const int j  = tid & 127;
    const int kh = tid >> 7;

    __shared__ float hbuf[2][128];
    __shared__ float part[2][128];

    float w[64];
    {
        const float4* wp = (const float4*)(Whh + (size_t)j * 128 + (kh << 6));
#pragma unroll
        for (int i = 0; i < 16; i++) {
            const float4 v = wp[i];
            w[4 * i + 0] = v.x; w[4 * i + 1] = v.y;
            w[4 * i + 2] = v.z; w[4 * i + 3] = v.w;
        }
    }

    const unsigned short* xp_b = xp + (size_t)b * (T_SEQ * 128);
    float* out_b = out + (size_t)b * (T_SEQ * 128);

    float xpv = (tid < 128) ? hbits2f(xp_b[tid]) : 0.f;

    for (int t = 0; t < T_SEQ; t++) {
        float xpn = (tid < 128 && t + 1 < T_SEQ) ? hbits2f(xp_b[(t + 1) * 128 + tid]) : 0.f;

        float a0 = 0.f, a1 = 0.f, a2 = 0.f, a3 = 0.f;
        if (t > 0) {
            const float4* hq = (const float4*)(&hbuf[t & 1][kh << 6]);
#pragma unroll
            for (int i = 0; i < 16; i++) {
                const float4 h4 = hq[i];
                a0 = fmaf(w[4 * i + 0], h4.x, a0);
                a1 = fmaf(w[4 * i + 1], h4.y, a1);
                a2 = fmaf(w[4 * i + 2], h4.z, a2);
                a3 = fmaf(w[4 * i + 3], h4.w, a3);
            }
        }
        part[kh][j] = (a0 + a1) + (a2 + a3);
        __syncthreads();
        if (tid < 128) {
            const float v = part[0][tid] + part[1][tid] + xpv;
            const float h = tanhf(v);
            hbuf[(t + 1) & 1][tid] = h;
            out_b[t * 128 + tid] = h;
            if (t == T_SEQ - 1) hn[b * 128 + tid] = h;
        }
        __syncthreads();
        xpv = xpn;
    }
}

// =====================================================================
// Launch.  ws (bytes): r0w@0 16MB | r1h@16MB 16MB | xp2h@32MB 4MB |
//   hpk0@37,748,736 128KB | hpk1@37,879,808 128KB | prog0@38,010,880 1KB
// =====================================================================
extern "C" void kernel_launch(void* const* d_in, const int* in_sizes, int n_in,
                              void* d_out, int out_size, void* d_ws, size_t ws_size,
                              hipStream_t stream)
{
    const float* x    = (const float*)d_in[0];
    const float* Wih0 = (const float*)d_in[1];
    const float* Whh0 = (const float*)d_in[2];
    const float* bih0 = (const float*)d_in[3];
    const float* bhh0 = (const float*)d_in[4];
    const float* Wih1 = (const float*)d_in[5];
    const float* Whh1 = (const float*)d_in[6];
    const float* bih1 = (const float*)d_in[7];
    const float* bhh1 = (const float*)d_in[8];
    const float* Wih2 = (const float*)d_in[9];
    const float* Whh2 = (const float*)d_in[10];
    const float* bih2 = (const float*)d_in[11];
    const float* bhh2 = (const float*)d_in[12];

    char* wsb = (char*)d_ws;
    uint32_t*       r0w  = (uint32_t*)wsb;
    unsigned short* r1h  = (unsigned short*)(wsb + 16777216);
    unsigned short* xp2h = (unsigned short*)(wsb + 33554432);
    uint32_t*       hpk0 = (uint32_t*)(wsb + 37748736);
    uint32_t*       hpk1 = (uint32_t*)(wsb + 37879808);
    uint32_t*       prog0= (uint32_t*)(wsb + 38010880);

    float* out = (float*)d_out;            // [32,512,128]
    float* hn  = out + NB * T_SEQ * 128;   // [1,32,128]

    const int M = NB * T_SEQ;  // 16384

    rec512_fused<<<512, 1024, 0, stream>>>(x, Wih0, Whh0, bih0, bhh0,
                                           Wih1, Whh1, bih1, bhh1,
                                           r0w, r1h, hpk0, hpk1, prog0);
    gemm2h<<<dim3(M / BM, 1), 256, 0, stream>>>(r1h, Wih2, bih2, bhh2, xp2h, M, 512);
    rec128h<<<NB, 256, 0, stream>>>(Whh2, xp2h, out, hn);
}

// Round 2
// 1982.819 us; speedup vs baseline: 2.2283x; 2.2283x over previous
//
#include <hip/hip_runtime.h>
#include <hip/hip_fp16.h>
#include <cstdint>
#include <cstddef>
#include <cstring>

#define T_SEQ 512
#define NB 32

__device__ __forceinline__ uint32_t agent_load_u32(const uint32_t* p) {
    return __hip_atomic_load(p, __ATOMIC_RELAXED, __HIP_MEMORY_SCOPE_AGENT);
}
__device__ __forceinline__ void agent_store_u32(uint32_t* p, uint32_t v) {
    __hip_atomic_store(p, v, __ATOMIC_RELAXED, __HIP_MEMORY_SCOPE_AGENT);
}
__device__ __forceinline__ float hbits2f(unsigned short us) {
    __half h; __builtin_memcpy(&h, &us, 2); return __half2float(h);
}

// =====================================================================
// rec512_fused: layers 0 and 1 run CONCURRENTLY.
//   blocks   0..255 = layer-0 slices (b = bid&31, s = bid>>5)
//   blocks 256..511 = layer-1 slices (same decomposition; XCD = b%8 for
//                     both halves, so the handoff stays L2-local).
// launch_bounds(1024, 2): compiler free to allocate ~60 VGPR (baseline-
// proven). 60 <= 64 -> HW allows 8 waves/SIMD -> 2 blocks/CU co-resident.
// DO NOT set min-waves=8: r1 showed it forces a 64-reg budget, the
// allocator remats the whole weight array, and FETCH_SIZE explodes to
// 6.5 GB/dispatch (weights reloaded every step; 4 ms).
// Cross-layer handoff: l0 epilogue packs 64 relu outputs into 32 u32
// words, agent-stores to r0w[b][t][256], drains vmcnt(0), then bumps
// prog0[b][s]=t+1. l1's staging lanes poll prog0 >= t+2 then agent-load.
// Dependency is one-directional (l0 never waits on l1) => acyclic, no
// deadlock; losing co-residency only degrades to serial execution.
// Within-layer h exchange: unchanged parity-tagged hpk protocol.
// =====================================================================
__global__ __launch_bounds__(1024, 2) void rec512_fused(
    const float* __restrict__ x,
    const float* __restrict__ Wih0, const float* __restrict__ Whh0,
    const float* __restrict__ bih0, const float* __restrict__ bhh0,
    const float* __restrict__ Wih1, const float* __restrict__ Whh1,
    const float* __restrict__ bih1, const float* __restrict__ bhh1,
    uint32_t* __restrict__ r0w,        // [NB][T][256] relu0 fp16 pairs
    unsigned short* __restrict__ r1h,  // [NB][T][512] fp16 bits
    uint32_t* __restrict__ hpk0, uint32_t* __restrict__ hpk1,
    uint32_t* __restrict__ prog0)      // [NB][8] layer-0 step counters
{
    __shared__ float hbuf[2][512];
    __shared__ float abuf[2][512];     // l0: x staging (128 used); l1: relu0
    __shared__ float part[16][64];

    const int tid = threadIdx.x;
    const int bb  = blockIdx.x & 255;
    const int b   = bb & 31;
    const int s   = bb >> 5;           // 0..7
    const int jl  = tid & 63;
    const int kq  = tid >> 6;          // 0..15, wave-uniform
    const int row = (s << 6) + jl;
    const bool own = (kq == s);        // for tid<512 poll lanes
    const int myrow = (s << 6) + tid;  // epilogue lanes tid<64

    if (blockIdx.x < 256) {
        // ------------------------- layer 0 -------------------------
        __half2 wh[16], wi[4];
        {
            const float4* p4 = (const float4*)(Whh0 + (size_t)row * 512 + (kq << 5));
#pragma unroll
            for (int i = 0; i < 8; i++) {
                const float4 v = p4[i];
                wh[2 * i]     = __floats2half2_rn(v.x, v.y);
                wh[2 * i + 1] = __floats2half2_rn(v.z, v.w);
            }
            const float4* q4 = (const float4*)(Wih0 + (size_t)row * 128 + (kq << 3));
#pragma unroll
            for (int i = 0; i < 2; i++) {
                const float4 v = q4[i];
                wi[2 * i]     = __floats2half2_rn(v.x, v.y);
                wi[2 * i + 1] = __floats2half2_rn(v.z, v.w);
            }
        }
        float bias = 0.f;
        if (tid < 64) { const int r = (s << 6) + tid; bias = bih0[r] + bhh0[r]; }

        const float* x_b = x + (size_t)b * (T_SEQ * 128);
        uint32_t* r0_b = r0w + (size_t)b * (T_SEQ * 256);
        uint32_t* hp_b = hpk0 + (b << 10);

        if (tid < 128) abuf[0][tid] = x_b[tid];
        __syncthreads();

        for (int t = 0; t < T_SEQ; t++) {
            const int p = t & 1;
            float xn = 0.f;
            if (tid < 128 && t + 1 < T_SEQ) xn = x_b[(t + 1) * 128 + tid];

            if (t > 0 && tid < 512 && !own) {
                const uint32_t wtag = (uint32_t)t;
                uint32_t* sp = hp_b + (p << 9) + tid;
                uint32_t v;
                do { v = agent_load_u32(sp); } while ((v & 0xffffu) != wtag);
                hbuf[p][tid] = hbits2f((unsigned short)(v >> 16));
            }
            __syncthreads();   // B1
            if (tid < 128 && t + 1 < T_SEQ) abuf[(t + 1) & 1][tid] = xn;

            float a0 = 0.f, a1 = 0.f, a2 = 0.f, a3 = 0.f;
            if (t > 0) {
                const float4* hq = (const float4*)(&hbuf[p][kq << 5]);
#pragma unroll
                for (int i = 0; i < 8; i++) {
                    const float4 h4 = hq[i];
                    a0 = fmaf(__low2float(wh[2 * i]),      h4.x, a0);
                    a1 = fmaf(__high2float(wh[2 * i]),     h4.y, a1);
                    a2 = fmaf(__low2float(wh[2 * i + 1]),  h4.z, a2);
                    a3 = fmaf(__high2float(wh[2 * i + 1]), h4.w, a3);
                }
            }
            {
                const float4* xq = (const float4*)(&abuf[p][kq << 3]);
#pragma unroll
                for (int i = 0; i < 2; i++) {
                    const float4 x4 = xq[i];
                    a0 = fmaf(__low2float(wi[2 * i]),      x4.x, a0);
                    a1 = fmaf(__high2float(wi[2 * i]),     x4.y, a1);
                    a2 = fmaf(__low2float(wi[2 * i + 1]),  x4.z, a2);
                    a3 = fmaf(__high2float(wi[2 * i + 1]), x4.w, a3);
                }
            }
            part[kq][jl] = (a0 + a1) + (a2 + a3);
            __syncthreads();   // B2
            if (tid < 64) {
                const int p2 = (t + 1) & 1;
                float v = bias;
#pragma unroll
                for (int q = 0; q < 16; q++) v += part[q][tid];
                const float hv = tanhf(v);
                const __half hf = __float2half_rn(hv);
                unsigned short us; __builtin_memcpy(&us, &hf, 2);
                agent_store_u32(hp_b + (p2 << 9) + myrow,
                                ((uint32_t)us << 16) | (uint32_t)(t + 1));
                hbuf[p2][myrow] = hbits2f(us);
                // pack relu pairs: word w holds rows (2w, 2w+1) — same
                // layout the old u32 view of r0h had.
                const uint32_t ru = (us & 0x8000u) ? 0u : (uint32_t)us;
                const uint32_t vlo = (uint32_t)__shfl((int)ru, (tid << 1) & 63, 64);
                const uint32_t vhi = (uint32_t)__shfl((int)ru, ((tid << 1) + 1) & 63, 64);
                if (tid < 32)
                    agent_store_u32(r0_b + (size_t)t * 256 + (s << 5) + tid,
                                    (vhi << 16) | vlo);
                asm volatile("s_waitcnt vmcnt(0)" ::: "memory");
                if (tid == 0)
                    agent_store_u32(prog0 + (b << 3) + s, (uint32_t)(t + 1));
            }
            // next step's B1 orders everything else
        }
    } else {
        // ------------------------- layer 1 -------------------------
        __half2 wi[16], wh[16];
        {
            const float4* p4 = (const float4*)(Wih1 + (size_t)row * 512 + (kq << 5));
#pragma unroll
            for (int i = 0; i < 8; i++) {
                const float4 v = p4[i];
                wi[2 * i]     = __floats2half2_rn(v.x, v.y);
                wi[2 * i + 1] = __floats2half2_rn(v.z, v.w);
            }
            p4 = (const float4*)(Whh1 + (size_t)row * 512 + (kq << 5));
#pragma unroll
            for (int i = 0; i < 8; i++) {
                const float4 v = p4[i];
                wh[2 * i]     = __floats2half2_rn(v.x, v.y);
                wh[2 * i + 1] = __floats2half2_rn(v.z, v.w);
            }
        }
        float bias = 0.f;
        if (tid < 64) { const int r = (s << 6) + tid; bias = bih1[r] + bhh1[r]; }

        const uint32_t* r0_b = r0w + (size_t)b * (T_SEQ * 256);
        unsigned short* r1_b = r1h + (size_t)b * (T_SEQ * 512);
        uint32_t* hp_b = hpk1 + (b << 10);
        const int wlane = tid - 512;   // 0..255 staging lanes
        const bool stager = (tid >= 512 && tid < 768);
        const uint32_t* myprog = prog0 + (b << 3) + (stager ? (wlane >> 5) : 0);

        if (stager) {
            uint32_t pv;
            do { pv = agent_load_u32(myprog); } while (pv == 0u);   // l0 step 0 done
            asm volatile("" ::: "memory");
            const uint32_t v = agent_load_u32(r0_b + wlane);        // r0(0) pairs
            abuf[0][2 * wlane]     = hbits2f((unsigned short)(v & 0xffffu));
            abuf[0][2 * wlane + 1] = hbits2f((unsigned short)(v >> 16));
        }
        __syncthreads();

        for (int t = 0; t < T_SEQ; t++) {
            const int p = t & 1;
            uint32_t rn = 0;
            if (stager && t + 1 < T_SEQ) {
                const uint32_t need = (uint32_t)(t + 2);            // l0 step t+1 done
                uint32_t pv;
                do { pv = agent_load_u32(myprog); } while (pv < need);
                asm volatile("" ::: "memory");
                rn = agent_load_u32(r0_b + (size_t)(t + 1) * 256 + wlane);
            }
            if (t > 0 && tid < 512 && !own) {
                const uint32_t wtag = (uint32_t)t;
                uint32_t* sp = hp_b + (p << 9) + tid;
                uint32_t v;
                do { v = agent_load_u32(sp); } while ((v & 0xffffu) != wtag);
                hbuf[p][tid] = hbits2f((unsigned short)(v >> 16));
            }
            __syncthreads();   // B1
            if (stager && t + 1 < T_SEQ) {
                abuf[(t + 1) & 1][2 * wlane]     = hbits2f((unsigned short)(rn & 0xffffu));
                abuf[(t + 1) & 1][2 * wlane + 1] = hbits2f((unsigned short)(rn >> 16));
            }

            float a0 = 0.f, a1 = 0.f, a2 = 0.f, a3 = 0.f;
            {
                const float4* rq = (const float4*)(&abuf[p][kq << 5]);
#pragma unroll
                for (int i = 0; i < 8; i++) {
                    const float4 h4 = rq[i];
                    a0 = fmaf(__low2float(wi[2 * i]),      h4.x, a0);
                    a1 = fmaf(__high2float(wi[2 * i]),     h4.y, a1);
                    a2 = fmaf(__low2float(wi[2 * i + 1]),  h4.z, a2);
                    a3 = fmaf(__high2float(wi[2 * i + 1]), h4.w, a3);
                }
            }
            if (t > 0) {
                const float4* hq = (const float4*)(&hbuf[p][kq << 5]);
#pragma unroll
                for (int i = 0; i < 8; i++) {
                    const float4 h4 = hq[i];
                    a0 = fmaf(__low2float(wh[2 * i]),      h4.x, a0);
                    a1 = fmaf(__high2float(wh[2 * i]),     h4.y, a1);
                    a2 = fmaf(__low2float(wh[2 * i + 1]),  h4.z, a2);
                    a3 = fmaf(__high2float(wh[2 * i + 1]), h4.w, a3);
                }
            }
            part[kq][jl] = (a0 + a1) + (a2 + a3);
            __syncthreads();   // B2
            if (tid < 64) {
                const int p2 = (t + 1) & 1;
                float v = bias;
#pragma unroll
                for (int q = 0; q < 16; q++) v += part[q][tid];
                const float hv = tanhf(v);
                const __half hf = __float2half_rn(hv);
                unsigned short us; __builtin_memcpy(&us, &hf, 2);
                agent_store_u32(hp_b + (p2 << 9) + myrow,
                                ((uint32_t)us << 16) | (uint32_t)(t + 1));
                hbuf[p2][myrow] = hbits2f(us);
                r1_b[(size_t)t * 512 + myrow] = (us & 0x8000u) ? (unsigned short)0 : us;
            }
        }
    }
}

// =====================================================================
// gemm2h: xp2 = relu1(fp16) @ Wih2^T + (bi+bh), fp16 out. (proven r10)
// =====================================================================
#define BM 64
#define BK 32
#define AS_STRIDE 68
#define BS_STRIDE 132

__global__ __launch_bounds__(256, 4) void gemm2h(
    const unsigned short* __restrict__ A,   // [M,512] fp16 bits
    const float* __restrict__ W,            // [128,512]
    const float* __restrict__ bi, const float* __restrict__ bh,
    unsigned short* __restrict__ C,         // [M,128] fp16 bits
    int M, int K)
{
    __shared__ float As[BK][AS_STRIDE];
    __shared__ float Bs[BK][BS_STRIDE];
    const int tid = threadIdx.x;
    const int tx = tid & 15, ty = tid >> 4;
    const int m0 = blockIdx.x * BM;
    const int lr = tid >> 3, lc = (tid & 7) << 2;

    float acc[4][8];
#pragma unroll
    for (int i = 0; i < 4; i++)
#pragma unroll
        for (int j = 0; j < 8; j++) acc[i][j] = 0.f;

    for (int k0 = 0; k0 < K; k0 += BK) {
#pragma unroll
        for (int p = 0; p < 2; p++) {
            const int m = p * 32 + lr;
            const uint2 u = *(const uint2*)(A + (size_t)(m0 + m) * K + k0 + lc);
            As[lc + 0][m] = hbits2f((unsigned short)(u.x & 0xffffu));
            As[lc + 1][m] = hbits2f((unsigned short)(u.x >> 16));
            As[lc + 2][m] = hbits2f((unsigned short)(u.y & 0xffffu));
            As[lc + 3][m] = hbits2f((unsigned short)(u.y >> 16));
        }
#pragma unroll
        for (int p = 0; p < 4; p++) {
            const int n = p * 32 + lr;
            const float4 b4 = *(const float4*)(W + (size_t)n * K + k0 + lc);
            Bs[lc + 0][n] = b4.x; Bs[lc + 1][n] = b4.y;
            Bs[lc + 2][n] = b4.z; Bs[lc + 3][n] = b4.w;
        }
        __syncthreads();
#pragma unroll
        for (int kk = 0; kk < BK; kk++) {
            const float4 a4  = *(const float4*)&As[kk][tx << 2];
            const float4 b4a = *(const float4*)&Bs[kk][ty << 3];
            const float4 b4b = *(const float4*)&Bs[kk][(ty << 3) + 4];
            const float a[4] = { a4.x, a4.y, a4.z, a4.w };
            const float b[8] = { b4a.x, b4a.y, b4a.z, b4a.w, b4b.x, b4b.y, b4b.z, b4b.w };
#pragma unroll
            for (int i = 0; i < 4; i++)
#pragma unroll
                for (int j = 0; j < 8; j++) acc[i][j] = fmaf(a[i], b[j], acc[i][j]);
        }
        __syncthreads();
    }
    const int nbase = ty << 3;
    const float4 bia = *(const float4*)(bi + nbase);
    const float4 bib = *(const float4*)(bi + nbase + 4);
    const float4 bha = *(const float4*)(bh + nbase);
    const float4 bhb = *(const float4*)(bh + nbase + 4);
    const float bt[8] = { bia.x + bha.x, bia.y + bha.y, bia.z + bha.z, bia.w + bha.w,
                          bib.x + bhb.x, bib.y + bhb.y, bib.z + bhb.z, bib.w + bhb.w };
#pragma unroll
    for (int i = 0; i < 4; i++) {
        const int row = m0 + (tx << 2) + i;
        uint32_t pk[4];
#pragma unroll
        for (int j = 0; j < 4; j++) {
            const __half hlo = __float2half_rn(acc[i][2 * j]     + bt[2 * j]);
            const __half hhi = __float2half_rn(acc[i][2 * j + 1] + bt[2 * j + 1]);
            unsigned short lo, hi;
            __builtin_memcpy(&lo, &hlo, 2); __builtin_memcpy(&hi, &hhi, 2);
            pk[j] = ((uint32_t)hi << 16) | lo;
        }
        *(uint4*)(C + (size_t)row * 128 + nbase) = make_uint4(pk[0], pk[1], pk[2], pk[3]);
    }
}

// =====================================================================
// Layer 2 recurrence (H=128), xp fp16. One WG/batch; LDS-only. (proven)
// =====================================================================
__global__ __launch_bounds__(256, 4) void rec128h(
    const float* __restrict__ Whh,          // [128,128]
    const unsigned short* __restrict__ xp,  // [NB,T,128] fp16 bits
    float* __restrict__ out,                // [NB,T,128]
    float* __restrict__ hn)                 // [NB,128]
{
    const int tid = threadIdx.x;
    const int b  = blockIdx.x;
    const int j  = tid & 127;
    const int kh = tid >> 7;

    __shared__ float hbuf[2][128];
    __shared__ float part[2][128];

    float w[64];
    {
        const float4* wp = (const float4*)(Whh + (size_t)j * 128 + (kh << 6));
#pragma unroll
        for (int i = 0; i < 16; i++) {
            const float4 v = wp[i];
            w[4 * i + 0] = v.x; w[4 * i + 1] = v.y;
            w[4 * i + 2] = v.z; w[4 * i + 3] = v.w;
        }
    }

    const unsigned short* xp_b = xp + (size_t)b * (T_SEQ * 128);
    float* out_b = out + (size_t)b * (T_SEQ * 128);

    float xpv = (tid < 128) ? hbits2f(xp_b[tid]) : 0.f;

    for (int t = 0; t < T_SEQ; t++) {
        float xpn = (tid < 128 && t + 1 < T_SEQ) ? hbits2f(xp_b[(t + 1) * 128 + tid]) : 0.f;

        float a0 = 0.f, a1 = 0.f, a2 = 0.f, a3 = 0.f;
        if (t > 0) {
            const float4* hq = (const float4*)(&hbuf[t & 1][kh << 6]);
#pragma unroll
            for (int i = 0; i < 16; i++) {
                const float4 h4 = hq[i];
                a0 = fmaf(w[4 * i + 0], h4.x, a0);
                a1 = fmaf(w[4 * i + 1], h4.y, a1);
                a2 = fmaf(w[4 * i + 2], h4.z, a2);
                a3 = fmaf(w[4 * i + 3], h4.w, a3);
            }
        }
        part[kh][j] = (a0 + a1) + (a2 + a3);
        __syncthreads();
        if (tid < 128) {
            const float v = part[0][tid] + part[1][tid] + xpv;
            const float h = tanhf(v);
            hbuf[(t + 1) & 1][tid] = h;
            out_b[t * 128 + tid] = h;
            if (t == T_SEQ - 1) hn[b * 128 + tid] = h;
        }
        __syncthreads();
        xpv = xpn;
    }
}

// =====================================================================
// Launch.  ws (bytes): r0w@0 16MB | r1h@16MB 16MB | xp2h@32MB 4MB |
//   hpk0@37,748,736 128KB | hpk1@37,879,808 128KB | prog0@38,010,880 1KB
// =====================================================================
extern "C" void kernel_launch(void* const* d_in, const int* in_sizes, int n_in,
                              void* d_out, int out_size, void* d_ws, size_t ws_size,
                              hipStream_t stream)
{
    const float* x    = (const float*)d_in[0];
    const float* Wih0 = (const float*)d_in[1];
    const float* Whh0 = (const float*)d_in[2];
    const float* bih0 = (const float*)d_in[3];
    const float* bhh0 = (const float*)d_in[4];
    const float* Wih1 = (const float*)d_in[5];
    const float* Whh1 = (const float*)d_in[6];
    const float* bih1 = (const float*)d_in[7];
    const float* bhh1 = (const float*)d_in[8];
    const float* Wih2 = (const float*)d_in[9];
    const float* Whh2 = (const float*)d_in[10];
    const float* bih2 = (const float*)d_in[11];
    const float* bhh2 = (const float*)d_in[12];

    char* wsb = (char*)d_ws;
    uint32_t*       r0w  = (uint32_t*)wsb;
    unsigned short* r1h  = (unsigned short*)(wsb + 16777216);
    unsigned short* xp2h = (unsigned short*)(wsb + 33554432);
    uint32_t*       hpk0 = (uint32_t*)(wsb + 37748736);
    uint32_t*       hpk1 = (uint32_t*)(wsb + 37879808);
    uint32_t*       prog0= (uint32_t*)(wsb + 38010880);

    float* out = (float*)d_out;            // [32,512,128]
    float* hn  = out + NB * T_SEQ * 128;   // [1,32,128]

    const int M = NB * T_SEQ;  // 16384

    rec512_fused<<<512, 1024, 0, stream>>>(x, Wih0, Whh0, bih0, bhh0,
                                           Wih1, Whh1, bih1, bhh1,
                                           r0w, r1h, hpk0, hpk1, prog0);
    gemm2h<<<dim3(M / BM, 1), 256, 0, stream>>>(r1h, Wih2, bih2, bhh2, xp2h, M, 512);
    rec128h<<<NB, 256, 0, stream>>>(Whh2, xp2h, out, hn);
}